// Round 13
// baseline (136.550 us; speedup 1.0000x reference)
//
#include <hip/hip_runtime.h>

// Playlist model: gathers -> concat [B,1920] -> low-rank cross -> MLP -> L2 norm.
// bf16 MFMA GEMMs (16x16x32), fp32 accumulate, double-buffered LDS prefetch,
// XCD-bijective block swizzle.  R12 structure; G4 at 32x64 @ 2048 blocks
// (6 blocks/CU, LDS-limited) — following the proven blocks/CU lever.

constexpr int B_ = 8192;
constexpr int D_ = 128;
constexpr int L_ = 5;
constexpr int F_ = 1920;   // 15 * 128
constexpr int P_ = 100;    // cross rank (padded to 128)
constexpr int NLOOK = 51;  // 6 single + 9*5 pooled lookups per row

typedef __attribute__((ext_vector_type(8))) short short8;
typedef __attribute__((ext_vector_type(4))) float f32x4;

__device__ __forceinline__ unsigned short f2bf(float x) {
  union { float f; unsigned int u; } v; v.f = x;
  unsigned int r = v.u + 0x7FFF + ((v.u >> 16) & 1);   // RNE
  return (unsigned short)(r >> 16);
}
__device__ __forceinline__ float bf2f(unsigned short b) {
  union { unsigned int u; float f; } v; v.u = ((unsigned int)b) << 16;
  return v.f;
}

__device__ __forceinline__ void gload_lds16(const void* g, void* l) {
  __builtin_amdgcn_global_load_lds(
      (const __attribute__((address_space(1))) void*)g,
      (__attribute__((address_space(3))) void*)l, 16, 0, 0);
}

// ---------------- gather + pool + weight transposes (one launch) ----------------
struct GatherArgs {
  const int*   idx[15];
  const float* tab[15];
};
struct TransBatch {
  const float* src[5];
  unsigned short* dst[5];
  int R[5], C[5], Cpad[5], Rpad[5], tiles_c[5], tile0[6];
};

// smem: raw rows [52][512B] + addrs[52] (u64) + ivals[52] (int)
constexpr int SMEM_RAW   = 52 * 512;
constexpr int SMEM_ADDR  = SMEM_RAW;            // +52*8
constexpr int SMEM_IVAL  = SMEM_ADDR + 52 * 8;  // +52*4
constexpr int SMEM_BYTES = SMEM_IVAL + 52 * 4;

__global__ __launch_bounds__(256)
void prep_kernel(GatherArgs ga, unsigned short* __restrict__ X, TransBatch tb) {
  __shared__ __align__(16) char smem[SMEM_BYTES];
  if ((int)blockIdx.x < B_) {
    // ================= gather: one batch row per block =================
    const int b = blockIdx.x;
    const int t = threadIdx.x;
    float* rawf = (float*)smem;
    unsigned long long* addrs = (unsigned long long*)(smem + SMEM_ADDR);
    int* ivals = (int*)(smem + SMEM_IVAL);

    // ---- phase 0: resolve per-lookup table addresses ----
    if (t < NLOOK) {
      int s, l;
      if (t < 6) { s = t; l = 0; }
      else { const int p = t - 6; s = 6 + p / 5; l = p - (p / 5) * 5; }
      const int* ip = nullptr; const float* tp = nullptr;
#pragma unroll
      for (int ss = 0; ss < 15; ++ss)
        if (ss == s) { ip = ga.idx[ss]; tp = ga.tab[ss]; }
      const int iv = (t < 6) ? ip[b] : ip[b * L_ + l];
      addrs[t] = (unsigned long long)(tp + (size_t)iv * D_);
      ivals[t] = iv;
    }
    __syncthreads();

    // ---- phase 1: stage all 51 table rows (512B each) into LDS ----
    {
      const int wave = t >> 6, lane = t & 63;
      for (int j = wave; j < 26; j += 4) {       // pair j covers lookups 2j, 2j+1
        const int lid = 2 * j + (lane >> 5);
        if (lid < NLOOK) {
          const char* g = (const char*)addrs[lid] + (size_t)(lane & 31) * 16;
          gload_lds16(g, smem + j * 1024);       // wave-uniform LDS base
        }
      }
    }
    __syncthreads();

    // ---- phase 2: reduce, bf16-convert, coalesced write ----
    if (t < 240) {
      const int s  = t >> 4;          // slot 0..14
      const int d0 = (t & 15) * 8;    // 8 dims per thread
      float v[8];
      if (s < 6) {
#pragma unroll
        for (int jj = 0; jj < 8; ++jj) v[jj] = rawf[s * 128 + d0 + jj];
      } else {
        const bool masked = (s < 11) || (s == 14);   // 11..13 plain mean
        const int pl0 = 6 + (s - 6) * 5;
        float cnt = 0.f;
#pragma unroll
        for (int jj = 0; jj < 8; ++jj) v[jj] = 0.f;
#pragma unroll
        for (int l = 0; l < L_; ++l) {
          const int iv = ivals[pl0 + l];
          if (!masked || iv != 0) {
            cnt += 1.f;
#pragma unroll
            for (int jj = 0; jj < 8; ++jj) v[jj] += rawf[(pl0 + l) * 128 + d0 + jj];
          }
        }
        const float inv = 1.f / (masked ? fmaxf(cnt, 1.f) : (float)L_);
#pragma unroll
        for (int jj = 0; jj < 8; ++jj) v[jj] *= inv;
      }
      short8 o;
#pragma unroll
      for (int jj = 0; jj < 8; ++jj) o[jj] = (short)f2bf(v[jj]);
      *(short8*)(X + (size_t)b * F_ + t * 8) = o;
    }
  } else {
    // ================= transpose+pad fp32 -> bf16 =================
    float (*tile)[33] = (float(*)[33])smem;   // 32x33 floats fits in smem
    const int id = blockIdx.x - B_;
    int d = 0;
#pragma unroll
    for (int i = 1; i < 5; ++i) if (id >= tb.tile0[i]) d = i;
    const int lid = id - tb.tile0[d];
    const int tcn = tb.tiles_c[d];
    const int tr = lid / tcn, tc = lid - tr * tcn;
    const float* src = tb.src[d];
    unsigned short* dst = tb.dst[d];
    const int R = tb.R[d], C = tb.C[d], Cpad = tb.Cpad[d], Rpad = tb.Rpad[d];
    const int r0 = tr * 32, c0 = tc * 32;
    const int tx = threadIdx.x & 31, ty = threadIdx.x >> 5;  // 32 x 8
#pragma unroll
    for (int i = 0; i < 32; i += 8) {
      const int r = r0 + ty + i, c = c0 + tx;
      tile[ty + i][tx] = (r < R && c < C) ? src[(size_t)r * C + c] : 0.f;
    }
    __syncthreads();
#pragma unroll
    for (int i = 0; i < 32; i += 8) {
      const int c = c0 + ty + i, r = r0 + tx;
      if (c < Cpad && r < Rpad)
        dst[(size_t)c * Rpad + r] = f2bf(tile[tx][ty + i]);
    }
  }
}

// ---------------- bf16 MFMA GEMM: C[M,N] = A[M,K] @ Bt[N,K]^T ----------------
// BMxBN tile, BK=64, 4 waves (2x2), DBUF = double-buffered LDS prefetch.
// EPI: 0 = +bias -> fp32 | 1 = +bias,ReLU -> bf16 | 2 = pad-store -> bf16 (col<Nvalid else 0)
//      3 = cross: x*(acc+bias)+x -> bf16 in place (Cb is both input x and output)
template<int EPI, int BM, int BN, bool DBUF>
__global__ __launch_bounds__(256)
void mfma_gemm(const unsigned short* __restrict__ A, const unsigned short* __restrict__ Bt,
               const float* __restrict__ bias, float* __restrict__ Cf,
               unsigned short* __restrict__ Cb, int M, int N, int K, int Nvalid)
{
  constexpr int BK = 64;
  constexpr int NB = DBUF ? 2 : 1;
  constexpr int WM = BM / 2, WN = BN / 2;
  constexpr int NFM = WM / 16, NFN = WN / 16;
  __shared__ __align__(16) unsigned short As[NB][BM * BK];
  __shared__ __align__(16) unsigned short Bs[NB][BN * BK];

  // XCD-bijective swizzle (requires gridDim.x*gridDim.y % 8 == 0)
  const int nwg  = gridDim.x * gridDim.y;
  const int wgid = blockIdx.y * gridDim.x + blockIdx.x;
  const int q    = nwg >> 3;
  const int sid  = (wgid & 7) * q + (wgid >> 3);
  const int bx   = sid % gridDim.x, by = sid / gridDim.x;

  const int tid  = threadIdx.x;
  const int wave = tid >> 6, lane = tid & 63;
  const int row0 = by * BM;
  const int n0   = bx * BN;
  const int wr = (wave >> 1) * WM, wc = (wave & 1) * WN;
  const int srow = lane >> 3;
  const int gc   = (lane & 7) ^ srow;

  f32x4 acc[NFM][NFN];
#pragma unroll
  for (int m = 0; m < NFM; ++m)
#pragma unroll
    for (int n = 0; n < NFN; ++n)
      acc[m][n] = (f32x4){0.f, 0.f, 0.f, 0.f};

  const size_t abase = (size_t)(row0 + srow) * K + (size_t)gc * 8;
  const size_t bbase = (size_t)(n0   + srow) * K + (size_t)gc * 8;

  auto stage = [&](int buf, int k0) {
#pragma unroll
    for (int i = 0; i < BM / 32; ++i) {
      const int s = wave * (BM / 32) + i;
      gload_lds16(A + abase + (size_t)s * 8 * K + k0, As[buf] + s * 512);
    }
#pragma unroll
    for (int i = 0; i < BN / 32; ++i) {
      const int s = wave * (BN / 32) + i;
      gload_lds16(Bt + bbase + (size_t)s * 8 * K + k0, Bs[buf] + s * 512);
    }
  };

  auto compute = [&](int buf) {
#pragma unroll
    for (int ks = 0; ks < 2; ++ks) {
      short8 af[NFM], bfr[NFN];
#pragma unroll
      for (int m = 0; m < NFM; ++m) {
        const int r  = wr + m * 16 + (lane & 15);
        const int cs = (ks * 4 + (lane >> 4)) ^ (r & 7);
        af[m] = *(const short8*)(As[buf] + r * 64 + cs * 8);
      }
#pragma unroll
      for (int n = 0; n < NFN; ++n) {
        const int r  = wc + n * 16 + (lane & 15);
        const int cs = (ks * 4 + (lane >> 4)) ^ (r & 7);
        bfr[n] = *(const short8*)(Bs[buf] + r * 64 + cs * 8);
      }
#pragma unroll
      for (int m = 0; m < NFM; ++m)
#pragma unroll
        for (int n = 0; n < NFN; ++n)
          acc[m][n] = __builtin_amdgcn_mfma_f32_16x16x32_bf16(af[m], bfr[n], acc[m][n], 0, 0, 0);
    }
  };

  const int nk = K / BK;
  if (!DBUF) {
    for (int t = 0; t < nk; ++t) {
      stage(0, t * BK);
      __syncthreads();
      compute(0);
      __syncthreads();
    }
  } else {
    stage(0, 0);
    __syncthreads();
    int cur = 0;
    for (int t = 0; t + 1 < nk; ++t) {
      stage(cur ^ 1, (t + 1) * BK);
      compute(cur);
      __syncthreads();
      cur ^= 1;
    }
    compute(cur);
  }

  const int l15 = lane & 15, l4 = lane >> 4;
#pragma unroll
  for (int m = 0; m < NFM; ++m) {
#pragma unroll
    for (int n = 0; n < NFN; ++n) {
      const int col = n0 + wc + n * 16 + l15;
      const float bv = (EPI == 2) ? 0.f : bias[col];
#pragma unroll
      for (int r = 0; r < 4; ++r) {
        const int row = row0 + wr + m * 16 + l4 * 4 + r;
        const float v = acc[m][n][r];
        if (EPI == 0) {
          Cf[(size_t)row * N + col] = v + bv;
        } else if (EPI == 1) {
          Cb[(size_t)row * N + col] = f2bf(fmaxf(v + bv, 0.f));
        } else if (EPI == 2) {
          Cb[(size_t)row * N + col] = (col < Nvalid) ? f2bf(v) : (unsigned short)0;
        } else {
          const float x = bf2f(Cb[(size_t)row * N + col]);
          Cb[(size_t)row * N + col] = f2bf(fmaf(x, v + bv, x));
        }
      }
    }
  }
}

// ---------------- L2 normalize rows of H [B,128] -> out fp32 ----------------
__global__ __launch_bounds__(256)
void l2norm_kernel(const float* __restrict__ H, float* __restrict__ out) {
  const int w    = threadIdx.x >> 6;
  const int lane = threadIdx.x & 63;
  const int b    = blockIdx.x * 4 + w;
  const float* hr = H + (size_t)b * 128;
  const float v0 = hr[lane];
  const float v1 = hr[lane + 64];
  float s = v0 * v0 + v1 * v1;
#pragma unroll
  for (int off = 32; off; off >>= 1) s += __shfl_xor(s, off);
  const float r = rsqrtf(fmaxf(s, 1e-12f));
  out[(size_t)b * 128 + lane]      = v0 * r;
  out[(size_t)b * 128 + lane + 64] = v1 * r;
}

extern "C" void kernel_launch(void* const* d_in, const int* in_sizes, int n_in,
                              void* d_out, int out_size, void* d_ws, size_t ws_size,
                              hipStream_t stream)
{
  GatherArgs ga;
  for (int s = 0; s < 15; ++s) {
    ga.idx[s] = (const int*)d_in[s];
    ga.tab[s] = (const float*)d_in[15 + s];
  }
  const float* cross_V = (const float*)d_in[30];  // [1920,100]
  const float* cross_U = (const float*)d_in[31];  // [100,1920]
  const float* cross_b = (const float*)d_in[32];  // [1920]
  const float* W0 = (const float*)d_in[33];       // [1920,512]
  const float* b0 = (const float*)d_in[34];
  const float* W1 = (const float*)d_in[35];       // [512,256]
  const float* b1 = (const float*)d_in[36];
  const float* W2 = (const float*)d_in[37];       // [256,128]
  const float* b2 = (const float*)d_in[38];

  char* w = (char*)d_ws;
  unsigned short* Xb  = (unsigned short*)w; w += (size_t)B_ * F_ * 2;    // [8192,1920] bf16
  unsigned short* t   = (unsigned short*)w; w += (size_t)B_ * 128 * 2;   // [8192,128] bf16 (pad 100->128)
  unsigned short* h0  = (unsigned short*)w; w += (size_t)B_ * 512 * 2;   // [8192,512] bf16
  unsigned short* h1  = (unsigned short*)w; w += (size_t)B_ * 256 * 2;   // [8192,256] bf16
  float*          h2  = (float*)w;          w += (size_t)B_ * 128 * 4;   // [8192,128] fp32
  unsigned short* Vt  = (unsigned short*)w; w += (size_t)128 * F_ * 2;   // [128,1920]
  unsigned short* Ut  = (unsigned short*)w; w += (size_t)F_ * 128 * 2;   // [1920,128]
  unsigned short* Wt0 = (unsigned short*)w; w += (size_t)512 * F_ * 2;   // [512,1920]
  unsigned short* Wt1 = (unsigned short*)w; w += (size_t)256 * 512 * 2;  // [256,512]
  unsigned short* Wt2 = (unsigned short*)w; w += (size_t)128 * 256 * 2;  // [128,256]

  const dim3 tb(256);

  // weight-transpose descriptors (fp32 -> bf16, K-major, zero-padded)
  TransBatch tbt;
  const float* srcs[5] = {cross_V, cross_U, W0, W1, W2};
  unsigned short* dsts[5] = {Vt, Ut, Wt0, Wt1, Wt2};
  const int Rs[5]  = {F_, P_, F_, 512, 256};
  const int Cs[5]  = {P_, F_, 512, 256, 128};
  const int Cp[5]  = {128, F_, 512, 256, 128};
  const int Rp[5]  = {F_, 128, F_, 512, 256};
  int acc_t = 0;
  for (int i = 0; i < 5; ++i) {
    tbt.src[i] = srcs[i]; tbt.dst[i] = dsts[i];
    tbt.R[i] = Rs[i]; tbt.C[i] = Cs[i]; tbt.Cpad[i] = Cp[i]; tbt.Rpad[i] = Rp[i];
    tbt.tiles_c[i] = Cp[i] / 32;
    tbt.tile0[i] = acc_t;
    acc_t += (Rp[i] / 32) * (Cp[i] / 32);
  }
  tbt.tile0[5] = acc_t;

  // 1) gather + pool -> Xb (1 row/block), and all weight transposes, one launch
  prep_kernel<<<B_ + acc_t, tb, 0, stream>>>(ga, Xb, tbt);
  // 2) t = Xb @ V            [8192,128(100 valid)]   grid 2x256=512
  mfma_gemm<2, 32, 64, true><<<dim3(2, B_ / 32), tb, 0, stream>>>(
      Xb, Vt, nullptr, nullptr, t, B_, 128, F_, P_);
  // 3) Xb = x*(t @ U + b)+x  [8192,1920] in place    grid 15x64=960 (K=128: no dbuf)
  mfma_gemm<3, 128, 128, false><<<dim3(F_ / 128, B_ / 128), tb, 0, stream>>>(
      t, Ut, cross_b, nullptr, Xb, B_, F_, 128, F_);
  // 4) h0 = relu(Xb @ W0 + b0)   [8192,512]   grid 8x256=2048 (6 blocks/CU LDS-lim)
  mfma_gemm<1, 32, 64, true><<<dim3(512 / 64, B_ / 32), tb, 0, stream>>>(
      Xb, Wt0, b0, nullptr, h0, B_, 512, F_, 512);
  // 5) h1 = relu(h0 @ W1 + b1)   [8192,256]   grid 4x256=1024 (4 blocks/CU)
  mfma_gemm<1, 32, 64, true><<<dim3(256 / 64, B_ / 32), tb, 0, stream>>>(
      h0, Wt1, b1, nullptr, h1, B_, 256, 512, 256);
  // 6) h2 = h1 @ W2 + b2         [8192,128] fp32     grid 2x256=512
  mfma_gemm<0, 32, 64, true><<<dim3(128 / 64, B_ / 32), tb, 0, stream>>>(
      h1, Wt2, b2, h2, nullptr, B_, 128, 256, 128);
  // 7) L2 normalize -> out
  l2norm_kernel<<<B_ / 4, tb, 0, stream>>>(h2, (float*)d_out);
}

// Round 15
// 105.225 us; speedup vs baseline: 1.2977x; 1.2977x over previous
//
#include <hip/hip_runtime.h>

// Playlist model: gathers -> concat [B,1920] -> low-rank cross -> MLP -> L2 norm.
// bf16 MFMA GEMMs (16x16x32), fp32 accumulate, double-buffered LDS prefetch,
// XCD-bijective block swizzle.  G3 at 64x64@3840 SINGLE-buffered and
// OUT-OF-PLACE (Xb -> Xc) — keeps R14's occupancy win, removes the race
// suspects (nk=2 dbuf, LDS-full CU, in-place RMW).

constexpr int B_ = 8192;
constexpr int D_ = 128;
constexpr int L_ = 5;
constexpr int F_ = 1920;   // 15 * 128
constexpr int P_ = 100;    // cross rank (padded to 128)
constexpr int NLOOK = 51;  // 6 single + 9*5 pooled lookups per row

typedef __attribute__((ext_vector_type(8))) short short8;
typedef __attribute__((ext_vector_type(4))) float f32x4;

__device__ __forceinline__ unsigned short f2bf(float x) {
  union { float f; unsigned int u; } v; v.f = x;
  unsigned int r = v.u + 0x7FFF + ((v.u >> 16) & 1);   // RNE
  return (unsigned short)(r >> 16);
}
__device__ __forceinline__ float bf2f(unsigned short b) {
  union { unsigned int u; float f; } v; v.u = ((unsigned int)b) << 16;
  return v.f;
}

__device__ __forceinline__ void gload_lds16(const void* g, void* l) {
  __builtin_amdgcn_global_load_lds(
      (const __attribute__((address_space(1))) void*)g,
      (__attribute__((address_space(3))) void*)l, 16, 0, 0);
}

// ---------------- gather + pool + weight transposes (one launch) ----------------
struct GatherArgs {
  const int*   idx[15];
  const float* tab[15];
};
struct TransBatch {
  const float* src[5];
  unsigned short* dst[5];
  int R[5], C[5], Cpad[5], Rpad[5], tiles_c[5], tile0[6];
};

// smem: raw rows [52][512B] + addrs[52] (u64) + ivals[52] (int)
constexpr int SMEM_RAW   = 52 * 512;
constexpr int SMEM_ADDR  = SMEM_RAW;            // +52*8
constexpr int SMEM_IVAL  = SMEM_ADDR + 52 * 8;  // +52*4
constexpr int SMEM_BYTES = SMEM_IVAL + 52 * 4;

__global__ __launch_bounds__(256)
void prep_kernel(GatherArgs ga, unsigned short* __restrict__ X, TransBatch tb) {
  __shared__ __align__(16) char smem[SMEM_BYTES];
  if ((int)blockIdx.x < B_) {
    // ================= gather: one batch row per block =================
    const int b = blockIdx.x;
    const int t = threadIdx.x;
    float* rawf = (float*)smem;
    unsigned long long* addrs = (unsigned long long*)(smem + SMEM_ADDR);
    int* ivals = (int*)(smem + SMEM_IVAL);

    // ---- phase 0: resolve per-lookup table addresses ----
    if (t < NLOOK) {
      int s, l;
      if (t < 6) { s = t; l = 0; }
      else { const int p = t - 6; s = 6 + p / 5; l = p - (p / 5) * 5; }
      const int* ip = nullptr; const float* tp = nullptr;
#pragma unroll
      for (int ss = 0; ss < 15; ++ss)
        if (ss == s) { ip = ga.idx[ss]; tp = ga.tab[ss]; }
      const int iv = (t < 6) ? ip[b] : ip[b * L_ + l];
      addrs[t] = (unsigned long long)(tp + (size_t)iv * D_);
      ivals[t] = iv;
    }
    __syncthreads();

    // ---- phase 1: stage all 51 table rows (512B each) into LDS ----
    {
      const int wave = t >> 6, lane = t & 63;
      for (int j = wave; j < 26; j += 4) {       // pair j covers lookups 2j, 2j+1
        const int lid = 2 * j + (lane >> 5);
        if (lid < NLOOK) {
          const char* g = (const char*)addrs[lid] + (size_t)(lane & 31) * 16;
          gload_lds16(g, smem + j * 1024);       // wave-uniform LDS base
        }
      }
    }
    __syncthreads();

    // ---- phase 2: reduce, bf16-convert, coalesced write ----
    if (t < 240) {
      const int s  = t >> 4;          // slot 0..14
      const int d0 = (t & 15) * 8;    // 8 dims per thread
      float v[8];
      if (s < 6) {
#pragma unroll
        for (int jj = 0; jj < 8; ++jj) v[jj] = rawf[s * 128 + d0 + jj];
      } else {
        const bool masked = (s < 11) || (s == 14);   // 11..13 plain mean
        const int pl0 = 6 + (s - 6) * 5;
        float cnt = 0.f;
#pragma unroll
        for (int jj = 0; jj < 8; ++jj) v[jj] = 0.f;
#pragma unroll
        for (int l = 0; l < L_; ++l) {
          const int iv = ivals[pl0 + l];
          if (!masked || iv != 0) {
            cnt += 1.f;
#pragma unroll
            for (int jj = 0; jj < 8; ++jj) v[jj] += rawf[(pl0 + l) * 128 + d0 + jj];
          }
        }
        const float inv = 1.f / (masked ? fmaxf(cnt, 1.f) : (float)L_);
#pragma unroll
        for (int jj = 0; jj < 8; ++jj) v[jj] *= inv;
      }
      short8 o;
#pragma unroll
      for (int jj = 0; jj < 8; ++jj) o[jj] = (short)f2bf(v[jj]);
      *(short8*)(X + (size_t)b * F_ + t * 8) = o;
    }
  } else {
    // ================= transpose+pad fp32 -> bf16 =================
    float (*tile)[33] = (float(*)[33])smem;   // 32x33 floats fits in smem
    const int id = blockIdx.x - B_;
    int d = 0;
#pragma unroll
    for (int i = 1; i < 5; ++i) if (id >= tb.tile0[i]) d = i;
    const int lid = id - tb.tile0[d];
    const int tcn = tb.tiles_c[d];
    const int tr = lid / tcn, tc = lid - tr * tcn;
    const float* src = tb.src[d];
    unsigned short* dst = tb.dst[d];
    const int R = tb.R[d], C = tb.C[d], Cpad = tb.Cpad[d], Rpad = tb.Rpad[d];
    const int r0 = tr * 32, c0 = tc * 32;
    const int tx = threadIdx.x & 31, ty = threadIdx.x >> 5;  // 32 x 8
#pragma unroll
    for (int i = 0; i < 32; i += 8) {
      const int r = r0 + ty + i, c = c0 + tx;
      tile[ty + i][tx] = (r < R && c < C) ? src[(size_t)r * C + c] : 0.f;
    }
    __syncthreads();
#pragma unroll
    for (int i = 0; i < 32; i += 8) {
      const int c = c0 + ty + i, r = r0 + tx;
      if (c < Cpad && r < Rpad)
        dst[(size_t)c * Rpad + r] = f2bf(tile[tx][ty + i]);
    }
  }
}

// ---------------- bf16 MFMA GEMM: C[M,N] = A[M,K] @ Bt[N,K]^T ----------------
// BMxBN tile, BK=64, 4 waves (2x2), DBUF = double-buffered LDS prefetch.
// EPI: 0 = +bias -> fp32 | 1 = +bias,ReLU -> bf16 | 2 = pad-store -> bf16 (col<Nvalid else 0)
//      3 = cross OUT-OF-PLACE: Cb[row,col] = x*(acc+bias)+x with x = Xsrc[row,col]
template<int EPI, int BM, int BN, bool DBUF>
__global__ __launch_bounds__(256)
void mfma_gemm(const unsigned short* __restrict__ A, const unsigned short* __restrict__ Bt,
               const float* __restrict__ bias, float* __restrict__ Cf,
               unsigned short* __restrict__ Cb, const unsigned short* __restrict__ Xsrc,
               int M, int N, int K, int Nvalid)
{
  constexpr int BK = 64;
  constexpr int NB = DBUF ? 2 : 1;
  constexpr int WM = BM / 2, WN = BN / 2;
  constexpr int NFM = WM / 16, NFN = WN / 16;
  __shared__ __align__(16) unsigned short As[NB][BM * BK];
  __shared__ __align__(16) unsigned short Bs[NB][BN * BK];

  // XCD-bijective swizzle (requires gridDim.x*gridDim.y % 8 == 0)
  const int nwg  = gridDim.x * gridDim.y;
  const int wgid = blockIdx.y * gridDim.x + blockIdx.x;
  const int q    = nwg >> 3;
  const int sid  = (wgid & 7) * q + (wgid >> 3);
  const int bx   = sid % gridDim.x, by = sid / gridDim.x;

  const int tid  = threadIdx.x;
  const int wave = tid >> 6, lane = tid & 63;
  const int row0 = by * BM;
  const int n0   = bx * BN;
  const int wr = (wave >> 1) * WM, wc = (wave & 1) * WN;
  const int srow = lane >> 3;
  const int gc   = (lane & 7) ^ srow;

  f32x4 acc[NFM][NFN];
#pragma unroll
  for (int m = 0; m < NFM; ++m)
#pragma unroll
    for (int n = 0; n < NFN; ++n)
      acc[m][n] = (f32x4){0.f, 0.f, 0.f, 0.f};

  const size_t abase = (size_t)(row0 + srow) * K + (size_t)gc * 8;
  const size_t bbase = (size_t)(n0   + srow) * K + (size_t)gc * 8;

  auto stage = [&](int buf, int k0) {
#pragma unroll
    for (int i = 0; i < BM / 32; ++i) {
      const int s = wave * (BM / 32) + i;
      gload_lds16(A + abase + (size_t)s * 8 * K + k0, As[buf] + s * 512);
    }
#pragma unroll
    for (int i = 0; i < BN / 32; ++i) {
      const int s = wave * (BN / 32) + i;
      gload_lds16(Bt + bbase + (size_t)s * 8 * K + k0, Bs[buf] + s * 512);
    }
  };

  auto compute = [&](int buf) {
#pragma unroll
    for (int ks = 0; ks < 2; ++ks) {
      short8 af[NFM], bfr[NFN];
#pragma unroll
      for (int m = 0; m < NFM; ++m) {
        const int r  = wr + m * 16 + (lane & 15);
        const int cs = (ks * 4 + (lane >> 4)) ^ (r & 7);
        af[m] = *(const short8*)(As[buf] + r * 64 + cs * 8);
      }
#pragma unroll
      for (int n = 0; n < NFN; ++n) {
        const int r  = wc + n * 16 + (lane & 15);
        const int cs = (ks * 4 + (lane >> 4)) ^ (r & 7);
        bfr[n] = *(const short8*)(Bs[buf] + r * 64 + cs * 8);
      }
#pragma unroll
      for (int m = 0; m < NFM; ++m)
#pragma unroll
        for (int n = 0; n < NFN; ++n)
          acc[m][n] = __builtin_amdgcn_mfma_f32_16x16x32_bf16(af[m], bfr[n], acc[m][n], 0, 0, 0);
    }
  };

  const int nk = K / BK;
  if (!DBUF) {
    for (int t = 0; t < nk; ++t) {
      stage(0, t * BK);
      __syncthreads();
      compute(0);
      __syncthreads();
    }
  } else {
    stage(0, 0);
    __syncthreads();
    int cur = 0;
    for (int t = 0; t + 1 < nk; ++t) {
      stage(cur ^ 1, (t + 1) * BK);
      compute(cur);
      __syncthreads();
      cur ^= 1;
    }
    compute(cur);
  }

  const int l15 = lane & 15, l4 = lane >> 4;
#pragma unroll
  for (int m = 0; m < NFM; ++m) {
#pragma unroll
    for (int n = 0; n < NFN; ++n) {
      const int col = n0 + wc + n * 16 + l15;
      const float bv = (EPI == 2) ? 0.f : bias[col];
#pragma unroll
      for (int r = 0; r < 4; ++r) {
        const int row = row0 + wr + m * 16 + l4 * 4 + r;
        const float v = acc[m][n][r];
        if (EPI == 0) {
          Cf[(size_t)row * N + col] = v + bv;
        } else if (EPI == 1) {
          Cb[(size_t)row * N + col] = f2bf(fmaxf(v + bv, 0.f));
        } else if (EPI == 2) {
          Cb[(size_t)row * N + col] = (col < Nvalid) ? f2bf(v) : (unsigned short)0;
        } else {
          const float x = bf2f(Xsrc[(size_t)row * N + col]);
          Cb[(size_t)row * N + col] = f2bf(fmaf(x, v + bv, x));
        }
      }
    }
  }
}

// ---------------- L2 normalize rows of H [B,128] -> out fp32 ----------------
__global__ __launch_bounds__(256)
void l2norm_kernel(const float* __restrict__ H, float* __restrict__ out) {
  const int w    = threadIdx.x >> 6;
  const int lane = threadIdx.x & 63;
  const int b    = blockIdx.x * 4 + w;
  const float* hr = H + (size_t)b * 128;
  const float v0 = hr[lane];
  const float v1 = hr[lane + 64];
  float s = v0 * v0 + v1 * v1;
#pragma unroll
  for (int off = 32; off; off >>= 1) s += __shfl_xor(s, off);
  const float r = rsqrtf(fmaxf(s, 1e-12f));
  out[(size_t)b * 128 + lane]      = v0 * r;
  out[(size_t)b * 128 + lane + 64] = v1 * r;
}

extern "C" void kernel_launch(void* const* d_in, const int* in_sizes, int n_in,
                              void* d_out, int out_size, void* d_ws, size_t ws_size,
                              hipStream_t stream)
{
  GatherArgs ga;
  for (int s = 0; s < 15; ++s) {
    ga.idx[s] = (const int*)d_in[s];
    ga.tab[s] = (const float*)d_in[15 + s];
  }
  const float* cross_V = (const float*)d_in[30];  // [1920,100]
  const float* cross_U = (const float*)d_in[31];  // [100,1920]
  const float* cross_b = (const float*)d_in[32];  // [1920]
  const float* W0 = (const float*)d_in[33];       // [1920,512]
  const float* b0 = (const float*)d_in[34];
  const float* W1 = (const float*)d_in[35];       // [512,256]
  const float* b1 = (const float*)d_in[36];
  const float* W2 = (const float*)d_in[37];       // [256,128]
  const float* b2 = (const float*)d_in[38];

  char* w = (char*)d_ws;
  unsigned short* Xb  = (unsigned short*)w; w += (size_t)B_ * F_ * 2;    // [8192,1920] bf16
  unsigned short* Xc  = (unsigned short*)w; w += (size_t)B_ * F_ * 2;    // [8192,1920] bf16 (cross out)
  unsigned short* t   = (unsigned short*)w; w += (size_t)B_ * 128 * 2;   // [8192,128] bf16 (pad 100->128)
  unsigned short* h0  = (unsigned short*)w; w += (size_t)B_ * 512 * 2;   // [8192,512] bf16
  unsigned short* h1  = (unsigned short*)w; w += (size_t)B_ * 256 * 2;   // [8192,256] bf16
  float*          h2  = (float*)w;          w += (size_t)B_ * 128 * 4;   // [8192,128] fp32
  unsigned short* Vt  = (unsigned short*)w; w += (size_t)128 * F_ * 2;   // [128,1920]
  unsigned short* Ut  = (unsigned short*)w; w += (size_t)F_ * 128 * 2;   // [1920,128]
  unsigned short* Wt0 = (unsigned short*)w; w += (size_t)512 * F_ * 2;   // [512,1920]
  unsigned short* Wt1 = (unsigned short*)w; w += (size_t)256 * 512 * 2;  // [256,512]
  unsigned short* Wt2 = (unsigned short*)w; w += (size_t)128 * 256 * 2;  // [128,256]

  const dim3 tb(256);

  // weight-transpose descriptors (fp32 -> bf16, K-major, zero-padded)
  TransBatch tbt;
  const float* srcs[5] = {cross_V, cross_U, W0, W1, W2};
  unsigned short* dsts[5] = {Vt, Ut, Wt0, Wt1, Wt2};
  const int Rs[5]  = {F_, P_, F_, 512, 256};
  const int Cs[5]  = {P_, F_, 512, 256, 128};
  const int Cp[5]  = {128, F_, 512, 256, 128};
  const int Rp[5]  = {F_, 128, F_, 512, 256};
  int acc_t = 0;
  for (int i = 0; i < 5; ++i) {
    tbt.src[i] = srcs[i]; tbt.dst[i] = dsts[i];
    tbt.R[i] = Rs[i]; tbt.C[i] = Cs[i]; tbt.Cpad[i] = Cp[i]; tbt.Rpad[i] = Rp[i];
    tbt.tiles_c[i] = Cp[i] / 32;
    tbt.tile0[i] = acc_t;
    acc_t += (Rp[i] / 32) * (Cp[i] / 32);
  }
  tbt.tile0[5] = acc_t;

  // 1) gather + pool -> Xb (1 row/block), and all weight transposes, one launch
  prep_kernel<<<B_ + acc_t, tb, 0, stream>>>(ga, Xb, tbt);
  // 2) t = Xb @ V            [8192,128(100 valid)]   grid 2x256=512
  mfma_gemm<2, 32, 64, true><<<dim3(2, B_ / 32), tb, 0, stream>>>(
      Xb, Vt, nullptr, nullptr, t, nullptr, B_, 128, F_, P_);
  // 3) Xc = x*(t @ U + b)+x, x=Xb  [8192,1920]  grid 30x128=3840 (no dbuf, out-of-place)
  mfma_gemm<3, 64, 64, false><<<dim3(F_ / 64, B_ / 64), tb, 0, stream>>>(
      t, Ut, cross_b, nullptr, Xc, Xb, B_, F_, 128, F_);
  // 4) h0 = relu(Xc @ W0 + b0)   [8192,512]   grid 8x128=1024 (4 blocks/CU, proven)
  mfma_gemm<1, 64, 64, true><<<dim3(512 / 64, B_ / 64), tb, 0, stream>>>(
      Xc, Wt0, b0, nullptr, h0, nullptr, B_, 512, F_, 512);
  // 5) h1 = relu(h0 @ W1 + b1)   [8192,256]   grid 4x256=1024 (4 blocks/CU)
  mfma_gemm<1, 32, 64, true><<<dim3(256 / 64, B_ / 32), tb, 0, stream>>>(
      h0, Wt1, b1, nullptr, h1, nullptr, B_, 256, 512, 256);
  // 6) h2 = h1 @ W2 + b2         [8192,128] fp32     grid 2x256=512
  mfma_gemm<0, 32, 64, true><<<dim3(128 / 64, B_ / 32), tb, 0, stream>>>(
      h1, Wt2, b2, h2, nullptr, nullptr, B_, 128, 256, 128);
  // 7) L2 normalize -> out
  l2norm_kernel<<<B_ / 4, tb, 0, stream>>>(h2, (float*)d_out);
}

// Round 16
// 104.403 us; speedup vs baseline: 1.3079x; 1.0079x over previous
//
#include <hip/hip_runtime.h>

// Playlist model: gathers -> concat [B,1920] -> low-rank cross -> MLP -> L2 norm.
// bf16 MFMA GEMMs (16x16x32), fp32 accumulate, double-buffered LDS prefetch,
// XCD-bijective block swizzle.  R15 structure; final GEMM fuses the L2-norm
// epilogue (EPI=4, full 128-col row per block) -> no h2 buffer, no l2norm kernel.

constexpr int B_ = 8192;
constexpr int D_ = 128;
constexpr int L_ = 5;
constexpr int F_ = 1920;   // 15 * 128
constexpr int P_ = 100;    // cross rank (padded to 128)
constexpr int NLOOK = 51;  // 6 single + 9*5 pooled lookups per row

typedef __attribute__((ext_vector_type(8))) short short8;
typedef __attribute__((ext_vector_type(4))) float f32x4;

__device__ __forceinline__ unsigned short f2bf(float x) {
  union { float f; unsigned int u; } v; v.f = x;
  unsigned int r = v.u + 0x7FFF + ((v.u >> 16) & 1);   // RNE
  return (unsigned short)(r >> 16);
}
__device__ __forceinline__ float bf2f(unsigned short b) {
  union { unsigned int u; float f; } v; v.u = ((unsigned int)b) << 16;
  return v.f;
}

__device__ __forceinline__ void gload_lds16(const void* g, void* l) {
  __builtin_amdgcn_global_load_lds(
      (const __attribute__((address_space(1))) void*)g,
      (__attribute__((address_space(3))) void*)l, 16, 0, 0);
}

// ---------------- gather + pool + weight transposes (one launch) ----------------
struct GatherArgs {
  const int*   idx[15];
  const float* tab[15];
};
struct TransBatch {
  const float* src[5];
  unsigned short* dst[5];
  int R[5], C[5], Cpad[5], Rpad[5], tiles_c[5], tile0[6];
};

// smem: raw rows [52][512B] + addrs[52] (u64) + ivals[52] (int)
constexpr int SMEM_RAW   = 52 * 512;
constexpr int SMEM_ADDR  = SMEM_RAW;            // +52*8
constexpr int SMEM_IVAL  = SMEM_ADDR + 52 * 8;  // +52*4
constexpr int SMEM_BYTES = SMEM_IVAL + 52 * 4;

__global__ __launch_bounds__(256)
void prep_kernel(GatherArgs ga, unsigned short* __restrict__ X, TransBatch tb) {
  __shared__ __align__(16) char smem[SMEM_BYTES];
  if ((int)blockIdx.x < B_) {
    // ================= gather: one batch row per block =================
    const int b = blockIdx.x;
    const int t = threadIdx.x;
    float* rawf = (float*)smem;
    unsigned long long* addrs = (unsigned long long*)(smem + SMEM_ADDR);
    int* ivals = (int*)(smem + SMEM_IVAL);

    // ---- phase 0: resolve per-lookup table addresses ----
    if (t < NLOOK) {
      int s, l;
      if (t < 6) { s = t; l = 0; }
      else { const int p = t - 6; s = 6 + p / 5; l = p - (p / 5) * 5; }
      const int* ip = nullptr; const float* tp = nullptr;
#pragma unroll
      for (int ss = 0; ss < 15; ++ss)
        if (ss == s) { ip = ga.idx[ss]; tp = ga.tab[ss]; }
      const int iv = (t < 6) ? ip[b] : ip[b * L_ + l];
      addrs[t] = (unsigned long long)(tp + (size_t)iv * D_);
      ivals[t] = iv;
    }
    __syncthreads();

    // ---- phase 1: stage all 51 table rows (512B each) into LDS ----
    {
      const int wave = t >> 6, lane = t & 63;
      for (int j = wave; j < 26; j += 4) {       // pair j covers lookups 2j, 2j+1
        const int lid = 2 * j + (lane >> 5);
        if (lid < NLOOK) {
          const char* g = (const char*)addrs[lid] + (size_t)(lane & 31) * 16;
          gload_lds16(g, smem + j * 1024);       // wave-uniform LDS base
        }
      }
    }
    __syncthreads();

    // ---- phase 2: reduce, bf16-convert, coalesced write ----
    if (t < 240) {
      const int s  = t >> 4;          // slot 0..14
      const int d0 = (t & 15) * 8;    // 8 dims per thread
      float v[8];
      if (s < 6) {
#pragma unroll
        for (int jj = 0; jj < 8; ++jj) v[jj] = rawf[s * 128 + d0 + jj];
      } else {
        const bool masked = (s < 11) || (s == 14);   // 11..13 plain mean
        const int pl0 = 6 + (s - 6) * 5;
        float cnt = 0.f;
#pragma unroll
        for (int jj = 0; jj < 8; ++jj) v[jj] = 0.f;
#pragma unroll
        for (int l = 0; l < L_; ++l) {
          const int iv = ivals[pl0 + l];
          if (!masked || iv != 0) {
            cnt += 1.f;
#pragma unroll
            for (int jj = 0; jj < 8; ++jj) v[jj] += rawf[(pl0 + l) * 128 + d0 + jj];
          }
        }
        const float inv = 1.f / (masked ? fmaxf(cnt, 1.f) : (float)L_);
#pragma unroll
        for (int jj = 0; jj < 8; ++jj) v[jj] *= inv;
      }
      short8 o;
#pragma unroll
      for (int jj = 0; jj < 8; ++jj) o[jj] = (short)f2bf(v[jj]);
      *(short8*)(X + (size_t)b * F_ + t * 8) = o;
    }
  } else {
    // ================= transpose+pad fp32 -> bf16 =================
    float (*tile)[33] = (float(*)[33])smem;   // 32x33 floats fits in smem
    const int id = blockIdx.x - B_;
    int d = 0;
#pragma unroll
    for (int i = 1; i < 5; ++i) if (id >= tb.tile0[i]) d = i;
    const int lid = id - tb.tile0[d];
    const int tcn = tb.tiles_c[d];
    const int tr = lid / tcn, tc = lid - tr * tcn;
    const float* src = tb.src[d];
    unsigned short* dst = tb.dst[d];
    const int R = tb.R[d], C = tb.C[d], Cpad = tb.Cpad[d], Rpad = tb.Rpad[d];
    const int r0 = tr * 32, c0 = tc * 32;
    const int tx = threadIdx.x & 31, ty = threadIdx.x >> 5;  // 32 x 8
#pragma unroll
    for (int i = 0; i < 32; i += 8) {
      const int r = r0 + ty + i, c = c0 + tx;
      tile[ty + i][tx] = (r < R && c < C) ? src[(size_t)r * C + c] : 0.f;
    }
    __syncthreads();
#pragma unroll
    for (int i = 0; i < 32; i += 8) {
      const int c = c0 + ty + i, r = r0 + tx;
      if (c < Cpad && r < Rpad)
        dst[(size_t)c * Rpad + r] = f2bf(tile[tx][ty + i]);
    }
  }
}

// ---------------- bf16 MFMA GEMM: C[M,N] = A[M,K] @ Bt[N,K]^T ----------------
// BMxBN tile, BK=64, 4 waves (2x2), DBUF = double-buffered LDS prefetch.
// EPI: 0 = +bias -> fp32 | 1 = +bias,ReLU -> bf16 | 2 = pad-store -> bf16 (col<Nvalid else 0)
//      3 = cross OUT-OF-PLACE: Cb = x*(acc+bias)+x with x = Xsrc
//      4 = +bias, row L2-norm -> fp32 (requires BN == N == 128)
template<int EPI, int BM, int BN, bool DBUF>
__global__ __launch_bounds__(256)
void mfma_gemm(const unsigned short* __restrict__ A, const unsigned short* __restrict__ Bt,
               const float* __restrict__ bias, float* __restrict__ Cf,
               unsigned short* __restrict__ Cb, const unsigned short* __restrict__ Xsrc,
               int M, int N, int K, int Nvalid)
{
  constexpr int BK = 64;
  constexpr int NB = DBUF ? 2 : 1;
  constexpr int WM = BM / 2, WN = BN / 2;
  constexpr int NFM = WM / 16, NFN = WN / 16;
  __shared__ __align__(16) unsigned short As[NB][BM * BK];
  __shared__ __align__(16) unsigned short Bs[NB][BN * BK];
  __shared__ float H2[(EPI == 4) ? BM * 132 : 1];   // stride 132: bank-spread

  // XCD-bijective swizzle (requires gridDim.x*gridDim.y % 8 == 0)
  const int nwg  = gridDim.x * gridDim.y;
  const int wgid = blockIdx.y * gridDim.x + blockIdx.x;
  const int q    = nwg >> 3;
  const int sid  = (wgid & 7) * q + (wgid >> 3);
  const int bx   = sid % gridDim.x, by = sid / gridDim.x;

  const int tid  = threadIdx.x;
  const int wave = tid >> 6, lane = tid & 63;
  const int row0 = by * BM;
  const int n0   = bx * BN;
  const int wr = (wave >> 1) * WM, wc = (wave & 1) * WN;
  const int srow = lane >> 3;
  const int gc   = (lane & 7) ^ srow;

  f32x4 acc[NFM][NFN];
#pragma unroll
  for (int m = 0; m < NFM; ++m)
#pragma unroll
    for (int n = 0; n < NFN; ++n)
      acc[m][n] = (f32x4){0.f, 0.f, 0.f, 0.f};

  const size_t abase = (size_t)(row0 + srow) * K + (size_t)gc * 8;
  const size_t bbase = (size_t)(n0   + srow) * K + (size_t)gc * 8;

  auto stage = [&](int buf, int k0) {
#pragma unroll
    for (int i = 0; i < BM / 32; ++i) {
      const int s = wave * (BM / 32) + i;
      gload_lds16(A + abase + (size_t)s * 8 * K + k0, As[buf] + s * 512);
    }
#pragma unroll
    for (int i = 0; i < BN / 32; ++i) {
      const int s = wave * (BN / 32) + i;
      gload_lds16(Bt + bbase + (size_t)s * 8 * K + k0, Bs[buf] + s * 512);
    }
  };

  auto compute = [&](int buf) {
#pragma unroll
    for (int ks = 0; ks < 2; ++ks) {
      short8 af[NFM], bfr[NFN];
#pragma unroll
      for (int m = 0; m < NFM; ++m) {
        const int r  = wr + m * 16 + (lane & 15);
        const int cs = (ks * 4 + (lane >> 4)) ^ (r & 7);
        af[m] = *(const short8*)(As[buf] + r * 64 + cs * 8);
      }
#pragma unroll
      for (int n = 0; n < NFN; ++n) {
        const int r  = wc + n * 16 + (lane & 15);
        const int cs = (ks * 4 + (lane >> 4)) ^ (r & 7);
        bfr[n] = *(const short8*)(Bs[buf] + r * 64 + cs * 8);
      }
#pragma unroll
      for (int m = 0; m < NFM; ++m)
#pragma unroll
        for (int n = 0; n < NFN; ++n)
          acc[m][n] = __builtin_amdgcn_mfma_f32_16x16x32_bf16(af[m], bfr[n], acc[m][n], 0, 0, 0);
    }
  };

  const int nk = K / BK;
  if (!DBUF) {
    for (int t = 0; t < nk; ++t) {
      stage(0, t * BK);
      __syncthreads();
      compute(0);
      __syncthreads();
    }
  } else {
    stage(0, 0);
    __syncthreads();
    int cur = 0;
    for (int t = 0; t + 1 < nk; ++t) {
      stage(cur ^ 1, (t + 1) * BK);
      compute(cur);
      __syncthreads();
      cur ^= 1;
    }
    compute(cur);
  }

  const int l15 = lane & 15, l4 = lane >> 4;
#pragma unroll
  for (int m = 0; m < NFM; ++m) {
#pragma unroll
    for (int n = 0; n < NFN; ++n) {
      const int col = n0 + wc + n * 16 + l15;
      const float bv = (EPI == 2) ? 0.f : bias[col];
#pragma unroll
      for (int r = 0; r < 4; ++r) {
        const int row = row0 + wr + m * 16 + l4 * 4 + r;
        const float v = acc[m][n][r];
        if (EPI == 0) {
          Cf[(size_t)row * N + col] = v + bv;
        } else if (EPI == 1) {
          Cb[(size_t)row * N + col] = f2bf(fmaxf(v + bv, 0.f));
        } else if (EPI == 2) {
          Cb[(size_t)row * N + col] = (col < Nvalid) ? f2bf(v) : (unsigned short)0;
        } else if (EPI == 3) {
          const float x = bf2f(Xsrc[(size_t)row * N + col]);
          Cb[(size_t)row * N + col] = f2bf(fmaf(x, v + bv, x));
        } else {
          H2[(wr + m * 16 + l4 * 4 + r) * 132 + col] = v + bv;
        }
      }
    }
  }

  if (EPI == 4) {
    __syncthreads();
    // 8 threads per row, 16 consecutive floats each (BM == 32)
    const int row = tid >> 3;
    const int seg = tid & 7;
    const float* hr = H2 + row * 132 + seg * 16;
    float v[16];
    float s = 0.f;
#pragma unroll
    for (int j = 0; j < 16; ++j) { v[j] = hr[j]; s += v[j] * v[j]; }
#pragma unroll
    for (int off = 4; off; off >>= 1) s += __shfl_xor(s, off, 8);
    const float rs = rsqrtf(fmaxf(s, 1e-12f));
    float* op = Cf + (size_t)(row0 + row) * 128 + seg * 16;
#pragma unroll
    for (int j = 0; j < 16; ++j) op[j] = v[j] * rs;
  }
}

extern "C" void kernel_launch(void* const* d_in, const int* in_sizes, int n_in,
                              void* d_out, int out_size, void* d_ws, size_t ws_size,
                              hipStream_t stream)
{
  GatherArgs ga;
  for (int s = 0; s < 15; ++s) {
    ga.idx[s] = (const int*)d_in[s];
    ga.tab[s] = (const float*)d_in[15 + s];
  }
  const float* cross_V = (const float*)d_in[30];  // [1920,100]
  const float* cross_U = (const float*)d_in[31];  // [100,1920]
  const float* cross_b = (const float*)d_in[32];  // [1920]
  const float* W0 = (const float*)d_in[33];       // [1920,512]
  const float* b0 = (const float*)d_in[34];
  const float* W1 = (const float*)d_in[35];       // [512,256]
  const float* b1 = (const float*)d_in[36];
  const float* W2 = (const float*)d_in[37];       // [256,128]
  const float* b2 = (const float*)d_in[38];

  char* w = (char*)d_ws;
  unsigned short* Xb  = (unsigned short*)w; w += (size_t)B_ * F_ * 2;    // [8192,1920] bf16
  unsigned short* Xc  = (unsigned short*)w; w += (size_t)B_ * F_ * 2;    // [8192,1920] bf16 (cross out)
  unsigned short* t   = (unsigned short*)w; w += (size_t)B_ * 128 * 2;   // [8192,128] bf16 (pad 100->128)
  unsigned short* h0  = (unsigned short*)w; w += (size_t)B_ * 512 * 2;   // [8192,512] bf16
  unsigned short* h1  = (unsigned short*)w; w += (size_t)B_ * 256 * 2;   // [8192,256] bf16
  unsigned short* Vt  = (unsigned short*)w; w += (size_t)128 * F_ * 2;   // [128,1920]
  unsigned short* Ut  = (unsigned short*)w; w += (size_t)F_ * 128 * 2;   // [1920,128]
  unsigned short* Wt0 = (unsigned short*)w; w += (size_t)512 * F_ * 2;   // [512,1920]
  unsigned short* Wt1 = (unsigned short*)w; w += (size_t)256 * 512 * 2;  // [256,512]
  unsigned short* Wt2 = (unsigned short*)w; w += (size_t)128 * 256 * 2;  // [128,256]

  const dim3 tb(256);

  // weight-transpose descriptors (fp32 -> bf16, K-major, zero-padded)
  TransBatch tbt;
  const float* srcs[5] = {cross_V, cross_U, W0, W1, W2};
  unsigned short* dsts[5] = {Vt, Ut, Wt0, Wt1, Wt2};
  const int Rs[5]  = {F_, P_, F_, 512, 256};
  const int Cs[5]  = {P_, F_, 512, 256, 128};
  const int Cp[5]  = {128, F_, 512, 256, 128};
  const int Rp[5]  = {F_, 128, F_, 512, 256};
  int acc_t = 0;
  for (int i = 0; i < 5; ++i) {
    tbt.src[i] = srcs[i]; tbt.dst[i] = dsts[i];
    tbt.R[i] = Rs[i]; tbt.C[i] = Cs[i]; tbt.Cpad[i] = Cp[i]; tbt.Rpad[i] = Rp[i];
    tbt.tiles_c[i] = Cp[i] / 32;
    tbt.tile0[i] = acc_t;
    acc_t += (Rp[i] / 32) * (Cp[i] / 32);
  }
  tbt.tile0[5] = acc_t;

  // 1) gather + pool -> Xb (1 row/block), and all weight transposes, one launch
  prep_kernel<<<B_ + acc_t, tb, 0, stream>>>(ga, Xb, tbt);
  // 2) t = Xb @ V            [8192,128(100 valid)]   grid 2x256=512
  mfma_gemm<2, 32, 64, true><<<dim3(2, B_ / 32), tb, 0, stream>>>(
      Xb, Vt, nullptr, nullptr, t, nullptr, B_, 128, F_, P_);
  // 3) Xc = x*(t @ U + b)+x, x=Xb  [8192,1920]  grid 30x128=3840 (no dbuf, out-of-place)
  mfma_gemm<3, 64, 64, false><<<dim3(F_ / 64, B_ / 64), tb, 0, stream>>>(
      t, Ut, cross_b, nullptr, Xc, Xb, B_, F_, 128, F_);
  // 4) h0 = relu(Xc @ W0 + b0)   [8192,512]   grid 8x128=1024 (4 blocks/CU, proven)
  mfma_gemm<1, 64, 64, true><<<dim3(512 / 64, B_ / 64), tb, 0, stream>>>(
      Xc, Wt0, b0, nullptr, h0, nullptr, B_, 512, F_, 512);
  // 5) h1 = relu(h0 @ W1 + b1)   [8192,256]   grid 4x256=1024 (4 blocks/CU)
  mfma_gemm<1, 32, 64, true><<<dim3(256 / 64, B_ / 32), tb, 0, stream>>>(
      h0, Wt1, b1, nullptr, h1, nullptr, B_, 256, 512, 256);
  // 6+7) out = l2norm(h1 @ W2 + b2)  [8192,128] fused EPI=4   grid 1x256
  mfma_gemm<4, 32, 128, true><<<dim3(1, B_ / 32), tb, 0, stream>>>(
      h1, Wt2, b2, (float*)d_out, nullptr, nullptr, B_, 128, 256, 128);
}